// Round 11
// baseline (287.896 us; speedup 1.0000x reference)
//
#include <hip/hip_runtime.h>
#include <hip/hip_cooperative_groups.h>
#include <string.h>

// Segmented argmax (first-max tie-break), exact, ONE cooperative kernel:
//  P0 zero tbl/shd/found -> grid.sync
//  P1 seed: stream pred only; edges >= t gather dst sparsely, u64 atomicMax
//     pack into tbl (high edges fully processed).            -> grid.sync
//  P2 bitmap: bit i = (tbl[i]>>32) >= t (agent-scope loads). -> grid.sync
//  P3 main: bitmap in LDS (loaded ONCE per persistent block); low edge to
//     seeded node -> free skip; low edge to unseeded node -> shd-throttled
//     slow path + atomic; high edges already done.           -> grid.sync
//  P4 node epilogue (agent-scope tbl loads).
// Exactness: every >=t edge reaches the u64 atomicMax; skips require
// pred < t <= truemax (bitmap) or pred < shd <= truemax (slow path);
// equality always proceeds -> min-index tie-break via ~idx low word.
//
// Round-10 evidence: ~10-15us of inter-dispatch gaps (6 graph nodes) and
// 40MB of per-block bitmap reload were the remaining structural costs.
// Fusion deletes both. Model: stream ~4-6TB/s, random L2 loads ~280-385K/us,
// memory-side atomics ~26K/us.

namespace cg = cooperative_groups;

typedef float fx4 __attribute__((ext_vector_type(4)));
typedef int   ix4 __attribute__((ext_vector_type(4)));

#define CH 4          // vec4 chunks batched per thread per outer iteration
#define MAXW 4096     // LDS bitmap words (supports n <= 262144)
#define BLK 512
#define GRID 512      // 2 blocks/CU on 256 CUs: safely co-resident

__device__ __forceinline__ unsigned long long pack64(unsigned pbits, unsigned i) {
    return ((unsigned long long)pbits << 32) |
           (unsigned long long)(0xFFFFFFFFu - i);
}
__device__ __forceinline__ unsigned shadow_ld(const unsigned* p) {
    return __hip_atomic_load(p, __ATOMIC_RELAXED, __HIP_MEMORY_SCOPE_WORKGROUP);
}
__device__ __forceinline__ void shadow_st(unsigned* p, unsigned v) {
    __hip_atomic_store(p, v, __ATOMIC_RELAXED, __HIP_MEMORY_SCOPE_WORKGROUP);
}
__device__ __forceinline__ unsigned long long tbl_ld(const unsigned long long* p) {
    return __hip_atomic_load(p, __ATOMIC_RELAXED, __HIP_MEMORY_SCOPE_AGENT);
}

__global__ void __launch_bounds__(BLK, 4)
fused_kernel(const float* __restrict__ pred, const int* __restrict__ dst,
             const int* __restrict__ src, const int* __restrict__ matched,
             unsigned long long* __restrict__ tbl, unsigned* __restrict__ shd,
             unsigned long long* __restrict__ bmp,
             float* __restrict__ out_m, float* __restrict__ out_w,
             float* __restrict__ found, int e, int n, unsigned tbits) {
    __shared__ unsigned long long lbmp[MAXW];
    cg::grid_group grid = cg::this_grid();
    const int T = gridDim.x * blockDim.x;
    const int tid = blockIdx.x * blockDim.x + threadIdx.x;
    const int nvec = e >> 2;
    const int nwords = (n + 63) >> 6;

    // ---- P0: zero tables ----
    for (int i = tid; i < n; i += T) { tbl[i] = 0ULL; shd[i] = 0u; }
    if (tid == 0) *found = 0.0f;
    grid.sync();

    // ---- P1: seed (pred stream; sparse dst gather; atomics into tbl) ----
    for (int v0 = tid; v0 < nvec; v0 += T * CH) {
        fx4 p[CH]; int vi[CH]; bool ok[CH];
        #pragma unroll
        for (int c = 0; c < CH; ++c) {
            vi[c] = v0 + c * T;
            ok[c] = vi[c] < nvec;
            p[c] = ((const fx4*)pred)[ok[c] ? vi[c] : 0];
        }
        #pragma unroll
        for (int c = 0; c < CH; ++c) {
            unsigned pb[4] = {__float_as_uint(p[c].x), __float_as_uint(p[c].y),
                              __float_as_uint(p[c].z), __float_as_uint(p[c].w)};
            unsigned base = (unsigned)(vi[c] << 2);
            #pragma unroll
            for (int k = 0; k < 4; ++k) {
                if (ok[c] && pb[k] >= tbits) {
                    int d = dst[base + k];           // sparse gather (~2%)
                    (void)__hip_atomic_fetch_max(&tbl[d], pack64(pb[k], base + k),
                                                 __ATOMIC_RELAXED,
                                                 __HIP_MEMORY_SCOPE_AGENT);
                }
            }
        }
    }
    grid.sync();

    // ---- P2: bitmap (bit = node saw a >=t edge) ----
    for (int node = tid; node < (nwords << 6); node += T) {
        bool set = false;
        if (node < n)
            set = ((unsigned)(tbl_ld(&tbl[node]) >> 32)) >= tbits;
        unsigned long long mask = __ballot(set);
        if ((node & 63) == 0) bmp[node >> 6] = mask;
    }
    grid.sync();

    // ---- P3: main scan (bitmap in LDS, loaded once per persistent block) ----
    for (int w = threadIdx.x; w < nwords; w += blockDim.x) lbmp[w] = bmp[w];
    __syncthreads();

    for (int v0 = tid; v0 < nvec; v0 += T * CH) {
        fx4 p[CH]; ix4 d[CH]; int vi[CH]; bool ok[CH];
        #pragma unroll
        for (int c = 0; c < CH; ++c) {
            vi[c] = v0 + c * T;
            ok[c] = vi[c] < nvec;
            int a = ok[c] ? vi[c] : 0;
            p[c] = ((const fx4*)pred)[a];
            d[c] = ((const ix4*)dst)[a];
        }
        #pragma unroll
        for (int c = 0; c < CH; ++c) {
            unsigned pb[4] = {__float_as_uint(p[c].x), __float_as_uint(p[c].y),
                              __float_as_uint(p[c].z), __float_as_uint(p[c].w)};
            int dv[4] = {d[c].x, d[c].y, d[c].z, d[c].w};
            unsigned base = (unsigned)(vi[c] << 2);

            bool slow[4];
            unsigned cc[4] = {0, 0, 0, 0};
            #pragma unroll
            for (int k = 0; k < 4; ++k) {
                bool low = ok[c] && (pb[k] < tbits);   // high edges done in P1
                bool seeded = (lbmp[dv[k] >> 6] >> (dv[k] & 63)) & 1ULL;
                slow[k] = low && !seeded;
            }
            #pragma unroll
            for (int k = 0; k < 4; ++k)
                if (slow[k]) cc[k] = shadow_ld(&shd[dv[k]]);  // MLP on residual
            #pragma unroll
            for (int k = 0; k < 4; ++k) {
                if (slow[k] && pb[k] >= cc[k]) {
                    (void)__hip_atomic_fetch_max(&tbl[dv[k]],
                                                 pack64(pb[k], base + k),
                                                 __ATOMIC_RELAXED,
                                                 __HIP_MEMORY_SCOPE_AGENT);
                    shadow_st(&shd[dv[k]], pb[k]);  // throttle unseeded cascades
                }
            }
        }
    }
    // Tail (e % 4 edges): one thread, exact via slow path (idempotent max).
    if (tid == 0) {
        for (int i = (nvec << 2); i < e; ++i) {
            unsigned pb_ = __float_as_uint(pred[i]);
            int dd = dst[i];
            if (pb_ >= shadow_ld(&shd[dd])) {
                (void)__hip_atomic_fetch_max(&tbl[dd], pack64(pb_, (unsigned)i),
                                             __ATOMIC_RELAXED,
                                             __HIP_MEMORY_SCOPE_AGENT);
                shadow_st(&shd[dd], pb_);
            }
        }
    }
    grid.sync();

    // ---- P4: node epilogue ----
    for (int i = tid; i < n; i += T) {
        unsigned long long b = tbl_ld(&tbl[i]);
        int m = matched[i];
        int nm = m;
        float wp = 0.0f;
        if (b != 0ULL) {
            wp = __uint_as_float((unsigned)(b >> 32));
            unsigned idx = 0xFFFFFFFFu - (unsigned)(b & 0xFFFFFFFFu);
            if (m == -1 && wp > 0.5f) {
                nm = matched[src[idx]];
                *found = 1.0f;   // benign race: every writer stores 1.0f
            }
        }
        out_m[i] = (float)nm;
        out_w[i] = wp;
    }
}

extern "C" void kernel_launch(void* const* d_in, const int* in_sizes, int n_in,
                              void* d_out, int out_size, void* d_ws, size_t ws_size,
                              hipStream_t stream) {
    const float* edge_pred = (const float*)d_in[0];
    const int*   edge_index = (const int*)d_in[1];   // [2, E]: row0 = src, row1 = dst
    const int*   matched   = (const int*)d_in[2];

    int e = in_sizes[0];
    int n = in_sizes[2];

    const int* src = edge_index;
    const int* dst = edge_index + e;

    // ws layout: [ u64 tbl[n] | u32 shd[n] | u64 bmp[ceil(n/64)] ]
    unsigned long long* tbl = (unsigned long long*)d_ws;
    unsigned* shd = (unsigned*)(tbl + n);
    unsigned long long* bmp = (unsigned long long*)(shd + n);

    float* out_m = (float*)d_out;
    float* out_w = out_m + n;
    float* found = out_m + 2 * n;

    float ts = 0.98f;
    unsigned tbits;
    memcpy(&tbits, &ts, sizeof(tbits));

    void* args[] = {(void*)&edge_pred, (void*)&dst, (void*)&src, (void*)&matched,
                    (void*)&tbl, (void*)&shd, (void*)&bmp,
                    (void*)&out_m, (void*)&out_w, (void*)&found,
                    (void*)&e, (void*)&n, (void*)&tbits};
    (void)hipLaunchCooperativeKernel((const void*)fused_kernel,
                                     dim3(GRID), dim3(BLK), args, 0, stream);
}

// Round 12
// 79.556 us; speedup vs baseline: 3.6188x; 3.6188x over previous
//
#include <hip/hip_runtime.h>
#include <string.h>

// Segmented argmax (first-max tie-break), exact, four dispatches (R10 struct):
//  1. seed: stream PRED only (CH=8); edges >= t gather dst sparsely, filter
//     through shd, and u64-atomicMax directly into tbl (high edges done).
//  2. bitmap: bit i = (tbl[i]>>32) >= t (exact "node has a high edge").
//  3. main: stream pred+dst; high edge -> skip (done in seed); low edge to
//     seeded node -> LDS-bitmap skip (no global load); low edge to unseeded
//     node -> shd plain-store-throttled filter + atomic.
//  4. node epilogue.
// Exactness: every >=t edge reaches the u64 atomicMax (shd filter skips only
// if pred < shd <= truemax; equality proceeds); low-edge skips require
// pred < t <= truemax (bitmap) or pred < shd <= truemax (slow path);
// min-index tie-break via ~idx in the low word.
//
// Round-11 lesson: cooperative persistent-grid fusion ran the same byte
// traffic 4x slower (445 GB/s, 47% occ) -> flat dispatches win for streaming
// phases on MI355X. Reverted to R10; this round only shaves seed (CH=8 +
// shd-filtered seed atomics).

typedef float fx4 __attribute__((ext_vector_type(4)));
typedef int   ix4 __attribute__((ext_vector_type(4)));

#define CH 4    // main: vec4 chunks per thread
#define SCH 8   // seed: vec4 chunks per thread (pred-only stream)

__device__ __forceinline__ unsigned long long pack64(unsigned pbits, unsigned i) {
    return ((unsigned long long)pbits << 32) |
           (unsigned long long)(0xFFFFFFFFu - i);
}

__device__ __forceinline__ unsigned shadow_ld(const unsigned* p) {
    return __hip_atomic_load(p, __ATOMIC_RELAXED, __HIP_MEMORY_SCOPE_WORKGROUP);
}
__device__ __forceinline__ void shadow_st(unsigned* p, unsigned v) {
    __hip_atomic_store(p, v, __ATOMIC_RELAXED, __HIP_MEMORY_SCOPE_WORKGROUP);
}

// Pass 1: pred-only stream; high edges gather dst, shd-filter, atomicMax tbl.
__global__ void seed_pass(const float* __restrict__ pred,
                          const int* __restrict__ dst,
                          unsigned long long* __restrict__ tbl,
                          unsigned* __restrict__ shd,
                          int e, unsigned tbits) {
    const int nvec = e >> 2;
    const int T = gridDim.x * blockDim.x;
    const int t = blockIdx.x * blockDim.x + threadIdx.x;

    fx4 p[SCH];
    int vi[SCH];
    bool ok[SCH];
    #pragma unroll
    for (int c = 0; c < SCH; ++c) {
        vi[c] = t + c * T;
        ok[c] = vi[c] < nvec;
        p[c] = ((const fx4*)pred)[ok[c] ? vi[c] : 0];
    }
    #pragma unroll
    for (int c = 0; c < SCH; ++c) {
        unsigned pbv[4] = {__float_as_uint(p[c].x), __float_as_uint(p[c].y),
                           __float_as_uint(p[c].z), __float_as_uint(p[c].w)};
        unsigned base = (unsigned)(vi[c] << 2);
        #pragma unroll
        for (int k = 0; k < 4; ++k) {
            if (ok[c] && pbv[k] >= tbits) {
                int d = dst[base + k];              // sparse gather (~2%)
                if (pbv[k] >= shadow_ld(&shd[d])) { // filter same-node repeats
                    (void)__hip_atomic_fetch_max(&tbl[d], pack64(pbv[k], base + k),
                                                 __ATOMIC_RELAXED,
                                                 __HIP_MEMORY_SCOPE_AGENT);
                    shadow_st(&shd[d], pbv[k]);
                }
            }
        }
    }
}

// Pass 2: bitmap from tbl — bit i set iff node i saw a >=t edge in seed.
__global__ void bitmap_pass(const unsigned long long* __restrict__ tbl,
                            unsigned long long* __restrict__ bmp,
                            int n, unsigned tbits) {
    int node = blockIdx.x * blockDim.x + threadIdx.x;
    bool set = (node < n) && ((unsigned)(tbl[node] >> 32) >= tbits);
    unsigned long long mask = __ballot(set);
    if ((threadIdx.x & 63) == 0) {
        int w = node >> 6;
        if (w < ((n + 63) >> 6)) bmp[w] = mask;
    }
}

// Pass 3: low edges only; bitmap fast-skip, shd slow path for unseeded nodes.
__global__ void main_pass(const float* __restrict__ pred,
                          const int* __restrict__ dst,
                          unsigned long long* __restrict__ tbl,
                          unsigned* __restrict__ shd,
                          const unsigned long long* __restrict__ bmp,
                          int e, int n, unsigned tbits) {
    extern __shared__ unsigned long long lbmp[];
    const int nwords = (n + 63) >> 6;
    for (int w = threadIdx.x; w < nwords; w += blockDim.x)
        lbmp[w] = bmp[w];
    __syncthreads();

    const int nvec = e >> 2;
    const int T = gridDim.x * blockDim.x;
    const int t = blockIdx.x * blockDim.x + threadIdx.x;

    fx4 p[CH];
    ix4 d[CH];
    int vi[CH];
    bool ok[CH];
    #pragma unroll
    for (int c = 0; c < CH; ++c) {
        vi[c] = t + c * T;
        ok[c] = vi[c] < nvec;
        int a = ok[c] ? vi[c] : 0;
        p[c] = ((const fx4*)pred)[a];
        d[c] = ((const ix4*)dst)[a];
    }

    #pragma unroll
    for (int c = 0; c < CH; ++c) {
        unsigned pbv[4] = {__float_as_uint(p[c].x), __float_as_uint(p[c].y),
                           __float_as_uint(p[c].z), __float_as_uint(p[c].w)};
        int dv[4] = {d[c].x, d[c].y, d[c].z, d[c].w};
        unsigned base = (unsigned)(vi[c] << 2);

        bool slow[4];
        unsigned cc[4] = {0, 0, 0, 0};
        #pragma unroll
        for (int k = 0; k < 4; ++k) {
            bool low = ok[c] && (pbv[k] < tbits);       // high edges done in seed
            bool seeded = (lbmp[dv[k] >> 6] >> (dv[k] & 63)) & 1ULL;
            slow[k] = low && !seeded;
        }
        #pragma unroll
        for (int k = 0; k < 4; ++k)
            if (slow[k]) cc[k] = shadow_ld(&shd[dv[k]]);   // MLP on residual
        #pragma unroll
        for (int k = 0; k < 4; ++k) {
            if (slow[k] && pbv[k] >= cc[k]) {
                (void)__hip_atomic_fetch_max(&tbl[dv[k]],
                                             pack64(pbv[k], base + k),
                                             __ATOMIC_RELAXED,
                                             __HIP_MEMORY_SCOPE_AGENT);
                shadow_st(&shd[dv[k]], pbv[k]);  // throttle unseeded cascades
            }
        }
    }

    // Tail (e % 4 edges): one thread, exact (idempotent max; spurious
    // admissions to seeded nodes harmless).
    if (blockIdx.x == 0 && threadIdx.x == 0) {
        for (int i = (nvec << 2); i < e; ++i) {
            unsigned pb_ = __float_as_uint(pred[i]);
            int dd = dst[i];
            if (pb_ >= shadow_ld(&shd[dd])) {
                (void)__hip_atomic_fetch_max(&tbl[dd], pack64(pb_, (unsigned)i),
                                             __ATOMIC_RELAXED,
                                             __HIP_MEMORY_SCOPE_AGENT);
                shadow_st(&shd[dd], pb_);
            }
        }
    }
}

__global__ void node_kernel(const unsigned long long* __restrict__ best,
                            const int* __restrict__ matched,
                            const int* __restrict__ src,
                            float* __restrict__ out_matched,
                            float* __restrict__ out_winpred,
                            float* __restrict__ found,
                            int n) {
    int i = blockIdx.x * blockDim.x + threadIdx.x;
    if (i >= n) return;
    unsigned long long b = best[i];
    int m = matched[i];
    int nm = m;
    float wp = 0.0f;
    if (b != 0ULL) {
        wp = __uint_as_float((unsigned int)(b >> 32));
        unsigned int idx = 0xFFFFFFFFu - (unsigned int)(b & 0xFFFFFFFFu);
        if (m == -1 && wp > 0.5f) {
            nm = matched[src[idx]];
            *found = 1.0f;   // benign race: every writer stores 1.0f
        }
    }
    out_matched[i] = (float)nm;
    out_winpred[i] = wp;
}

extern "C" void kernel_launch(void* const* d_in, const int* in_sizes, int n_in,
                              void* d_out, int out_size, void* d_ws, size_t ws_size,
                              hipStream_t stream) {
    const float* edge_pred = (const float*)d_in[0];
    const int*   edge_index = (const int*)d_in[1];   // [2, E]: row0 = src, row1 = dst
    const int*   matched   = (const int*)d_in[2];

    const int e = in_sizes[0];
    const int n = in_sizes[2];

    const int* src = edge_index;
    const int* dst = edge_index + e;

    // ws layout: [ u64 tbl[n] | u32 shd[n] | u64 bmp[ceil(n/64)] ]
    unsigned long long* tbl = (unsigned long long*)d_ws;
    unsigned* shd = (unsigned*)(tbl + n);
    unsigned long long* bmp = (unsigned long long*)(shd + n);
    const int nwords = (n + 63) >> 6;

    float* out_matched = (float*)d_out;
    float* out_winpred = out_matched + n;
    float* found       = out_matched + 2 * n;

    (void)hipMemsetAsync(tbl, 0, (size_t)n * 12, stream);  // tbl + shd
    (void)hipMemsetAsync(found, 0, sizeof(float), stream);

    float ts = 0.98f;
    unsigned tbits;
    memcpy(&tbits, &ts, sizeof(tbits));

    const int block = 512;
    const int nvec = e >> 2;

    int grid_s = ((nvec + SCH - 1) / SCH + block - 1) / block;
    if (grid_s < 1) grid_s = 1;
    seed_pass<<<grid_s, block, 0, stream>>>(edge_pred, dst, tbl, shd, e, tbits);

    int grid_b = (n + block - 1) / block;
    bitmap_pass<<<grid_b, block, 0, stream>>>(tbl, bmp, n, tbits);

    int grid_e = ((nvec + CH - 1) / CH + block - 1) / block;
    if (grid_e < 1) grid_e = 1;
    const size_t lds_bytes = (size_t)nwords * sizeof(unsigned long long);
    main_pass<<<grid_e, block, lds_bytes, stream>>>(
        edge_pred, dst, tbl, shd, bmp, e, n, tbits);

    int grid_n = (n + 255) / 256;
    node_kernel<<<grid_n, 256, 0, stream>>>(tbl, matched, src,
                                            out_matched, out_winpred, found, n);
}

// Round 13
// 72.339 us; speedup vs baseline: 3.9798x; 1.0998x over previous
//
#include <hip/hip_runtime.h>
#include <string.h>

// Segmented argmax (first-max tie-break), exact, four dispatches:
//  1. seed (R10-exact): stream pred (CH=4); edges >= t gather dst sparsely and
//     u64-atomicMax pack directly into tbl (atomics overlap the stream; do NOT
//     pre-filter them — R12 showed the filter's dependent load costs more).
//  2. bitmap: bit i = (tbl[i]>>32) >= t (exact "node has a high edge").
//  3. main (CH=8): stream pred+dst; high edge -> done in seed; low edge to
//     seeded node -> LDS-bitmap skip (no global load); low edge to unseeded
//     node -> shd plain-store-throttled filter + atomic.
//  4. node epilogue.
// Exactness: every >=t edge reaches the u64 atomicMax; low-edge skips require
// pred < t <= truemax (bitmap) or pred < shd <= truemax (slow path); equality
// always proceeds -> min-index tie-break via ~idx low word.
//
// History: R11 coop fusion 4x slower (flat dispatches win). R12 seed filter
// +9us (dependent load before overlapped atomics). This round: R10 seed
// verbatim; main CH=8 halves the per-block bitmap reload (39->20MB).

typedef float fx4 __attribute__((ext_vector_type(4)));
typedef int   ix4 __attribute__((ext_vector_type(4)));

#define CH 8     // main: vec4 chunks per thread (64 edges)
#define SCH 4    // seed: vec4 chunks per thread (R10-proven)

__device__ __forceinline__ unsigned long long pack64(unsigned pbits, unsigned i) {
    return ((unsigned long long)pbits << 32) |
           (unsigned long long)(0xFFFFFFFFu - i);
}

__device__ __forceinline__ unsigned shadow_ld(const unsigned* p) {
    return __hip_atomic_load(p, __ATOMIC_RELAXED, __HIP_MEMORY_SCOPE_WORKGROUP);
}
__device__ __forceinline__ void shadow_st(unsigned* p, unsigned v) {
    __hip_atomic_store(p, v, __ATOMIC_RELAXED, __HIP_MEMORY_SCOPE_WORKGROUP);
}

// Pass 1: pred-only stream; high edges gather dst and atomicMax into tbl.
__global__ void seed_pass(const float* __restrict__ pred,
                          const int* __restrict__ dst,
                          unsigned long long* __restrict__ tbl,
                          int e, unsigned tbits) {
    const int nvec = e >> 2;
    const int T = gridDim.x * blockDim.x;
    const int t = blockIdx.x * blockDim.x + threadIdx.x;

    fx4 p[SCH];
    int vi[SCH];
    bool ok[SCH];
    #pragma unroll
    for (int c = 0; c < SCH; ++c) {
        vi[c] = t + c * T;
        ok[c] = vi[c] < nvec;
        p[c] = ((const fx4*)pred)[ok[c] ? vi[c] : 0];
    }
    #pragma unroll
    for (int c = 0; c < SCH; ++c) {
        unsigned pbv[4] = {__float_as_uint(p[c].x), __float_as_uint(p[c].y),
                           __float_as_uint(p[c].z), __float_as_uint(p[c].w)};
        unsigned base = (unsigned)(vi[c] << 2);
        #pragma unroll
        for (int k = 0; k < 4; ++k) {
            if (ok[c] && pbv[k] >= tbits) {
                int d = dst[base + k];              // sparse gather (~2%)
                (void)__hip_atomic_fetch_max(&tbl[d], pack64(pbv[k], base + k),
                                             __ATOMIC_RELAXED,
                                             __HIP_MEMORY_SCOPE_AGENT);
            }
        }
    }
}

// Pass 2: bitmap from tbl — bit i set iff node i saw a >=t edge in seed.
__global__ void bitmap_pass(const unsigned long long* __restrict__ tbl,
                            unsigned long long* __restrict__ bmp,
                            int n, unsigned tbits) {
    int node = blockIdx.x * blockDim.x + threadIdx.x;
    bool set = (node < n) && ((unsigned)(tbl[node] >> 32) >= tbits);
    unsigned long long mask = __ballot(set);
    if ((threadIdx.x & 63) == 0) {
        int w = node >> 6;
        if (w < ((n + 63) >> 6)) bmp[w] = mask;
    }
}

// Pass 3: low edges only; bitmap fast-skip, shd slow path for unseeded nodes.
__global__ void main_pass(const float* __restrict__ pred,
                          const int* __restrict__ dst,
                          unsigned long long* __restrict__ tbl,
                          unsigned* __restrict__ shd,
                          const unsigned long long* __restrict__ bmp,
                          int e, int n, unsigned tbits) {
    extern __shared__ unsigned long long lbmp[];
    const int nwords = (n + 63) >> 6;
    for (int w = threadIdx.x; w < nwords; w += blockDim.x)
        lbmp[w] = bmp[w];
    __syncthreads();

    const int nvec = e >> 2;
    const int T = gridDim.x * blockDim.x;
    const int t = blockIdx.x * blockDim.x + threadIdx.x;

    #pragma unroll
    for (int c = 0; c < CH; ++c) {
        int v = t + c * T;
        bool ok = v < nvec;
        int a = ok ? v : 0;
        fx4 p = ((const fx4*)pred)[a];
        ix4 d = ((const ix4*)dst)[a];

        unsigned pbv[4] = {__float_as_uint(p.x), __float_as_uint(p.y),
                           __float_as_uint(p.z), __float_as_uint(p.w)};
        int dv[4] = {d.x, d.y, d.z, d.w};
        unsigned base = (unsigned)(v << 2);

        bool slow[4];
        unsigned cc[4] = {0, 0, 0, 0};
        #pragma unroll
        for (int k = 0; k < 4; ++k) {
            bool low = ok && (pbv[k] < tbits);          // high edges done in seed
            bool seeded = (lbmp[dv[k] >> 6] >> (dv[k] & 63)) & 1ULL;
            slow[k] = low && !seeded;
        }
        #pragma unroll
        for (int k = 0; k < 4; ++k)
            if (slow[k]) cc[k] = shadow_ld(&shd[dv[k]]);   // MLP on residual
        #pragma unroll
        for (int k = 0; k < 4; ++k) {
            if (slow[k] && pbv[k] >= cc[k]) {
                (void)__hip_atomic_fetch_max(&tbl[dv[k]],
                                             pack64(pbv[k], base + k),
                                             __ATOMIC_RELAXED,
                                             __HIP_MEMORY_SCOPE_AGENT);
                shadow_st(&shd[dv[k]], pbv[k]);  // throttle unseeded cascades
            }
        }
    }

    // Tail (e % 4 edges): one thread, exact (idempotent max).
    if (blockIdx.x == 0 && threadIdx.x == 0) {
        for (int i = (nvec << 2); i < e; ++i) {
            unsigned pb_ = __float_as_uint(pred[i]);
            int dd = dst[i];
            if (pb_ >= shadow_ld(&shd[dd])) {
                (void)__hip_atomic_fetch_max(&tbl[dd], pack64(pb_, (unsigned)i),
                                             __ATOMIC_RELAXED,
                                             __HIP_MEMORY_SCOPE_AGENT);
                shadow_st(&shd[dd], pb_);
            }
        }
    }
}

__global__ void node_kernel(const unsigned long long* __restrict__ best,
                            const int* __restrict__ matched,
                            const int* __restrict__ src,
                            float* __restrict__ out_matched,
                            float* __restrict__ out_winpred,
                            float* __restrict__ found,
                            int n) {
    int i = blockIdx.x * blockDim.x + threadIdx.x;
    if (i >= n) return;
    unsigned long long b = best[i];
    int m = matched[i];
    int nm = m;
    float wp = 0.0f;
    if (b != 0ULL) {
        wp = __uint_as_float((unsigned int)(b >> 32));
        unsigned int idx = 0xFFFFFFFFu - (unsigned int)(b & 0xFFFFFFFFu);
        if (m == -1 && wp > 0.5f) {
            nm = matched[src[idx]];
            *found = 1.0f;   // benign race: every writer stores 1.0f
        }
    }
    out_matched[i] = (float)nm;
    out_winpred[i] = wp;
}

extern "C" void kernel_launch(void* const* d_in, const int* in_sizes, int n_in,
                              void* d_out, int out_size, void* d_ws, size_t ws_size,
                              hipStream_t stream) {
    const float* edge_pred = (const float*)d_in[0];
    const int*   edge_index = (const int*)d_in[1];   // [2, E]: row0 = src, row1 = dst
    const int*   matched   = (const int*)d_in[2];

    const int e = in_sizes[0];
    const int n = in_sizes[2];

    const int* src = edge_index;
    const int* dst = edge_index + e;

    // ws layout: [ u64 tbl[n] | u32 shd[n] | u64 bmp[ceil(n/64)] ]
    unsigned long long* tbl = (unsigned long long*)d_ws;
    unsigned* shd = (unsigned*)(tbl + n);
    unsigned long long* bmp = (unsigned long long*)(shd + n);
    const int nwords = (n + 63) >> 6;

    float* out_matched = (float*)d_out;
    float* out_winpred = out_matched + n;
    float* found       = out_matched + 2 * n;

    (void)hipMemsetAsync(tbl, 0, (size_t)n * 12, stream);  // tbl + shd
    (void)hipMemsetAsync(found, 0, sizeof(float), stream);

    float ts = 0.98f;
    unsigned tbits;
    memcpy(&tbits, &ts, sizeof(tbits));

    const int block = 512;
    const int nvec = e >> 2;

    int grid_s = ((nvec + SCH - 1) / SCH + block - 1) / block;
    if (grid_s < 1) grid_s = 1;
    seed_pass<<<grid_s, block, 0, stream>>>(edge_pred, dst, tbl, e, tbits);

    int grid_b = (n + block - 1) / block;
    bitmap_pass<<<grid_b, block, 0, stream>>>(tbl, bmp, n, tbits);

    int grid_e = ((nvec + CH - 1) / CH + block - 1) / block;
    if (grid_e < 1) grid_e = 1;
    const size_t lds_bytes = (size_t)nwords * sizeof(unsigned long long);
    main_pass<<<grid_e, block, lds_bytes, stream>>>(
        edge_pred, dst, tbl, shd, bmp, e, n, tbits);

    int grid_n = (n + 255) / 256;
    node_kernel<<<grid_n, 256, 0, stream>>>(tbl, matched, src,
                                            out_matched, out_winpred, found, n);
}

// Round 14
// 65.978 us; speedup vs baseline: 4.3635x; 1.0964x over previous
//
#include <hip/hip_runtime.h>
#include <string.h>

// Segmented argmax (first-max tie-break), exact, R10 structure:
//  1. seed: stream pred (CH=4, loads upfront); edges >= t gather dst sparsely
//     and u64-atomicMax pack into tbl (unfiltered — atomics overlap stream;
//     R12 proved pre-filtering them costs more than it saves).
//  2. bitmap: bit i = (tbl[i]>>32) >= t; also zeroes `found` (saves a memset
//     dispatch).
//  3. main (R10-verbatim, CH=4, loads upfront): high edge -> done in seed;
//     low edge to seeded node -> LDS-bitmap skip; low edge to unseeded node
//     -> shd plain-store-throttled filter + atomic.
//  4. node epilogue.
// Exactness: every >=t edge reaches the u64 atomicMax; skips require
// pred < t <= truemax (bitmap) or pred < shd <= truemax (slow path); equality
// always proceeds -> min-index tie-break via ~idx low word. Degenerates to
// the (correct, slower) shadow-filter path on adversarial data.
//
// R13 lesson: bitmap reload already hidden (CH=8 null); R8 FETCH=52MB for a
// 102MB scan -> pred re-read is L3-hit; scans pace at ~3.4 TB/s regardless.
// R14: t=0.97 (residual 27%->14%, -1.6M random loads vs +128K overlapped
// seed atomics), main restored to R10's upfront-load form, -1 dispatch.

typedef float fx4 __attribute__((ext_vector_type(4)));
typedef int   ix4 __attribute__((ext_vector_type(4)));

#define CH 4    // vec4 chunks per thread (16 edges), loads issued upfront

__device__ __forceinline__ unsigned long long pack64(unsigned pbits, unsigned i) {
    return ((unsigned long long)pbits << 32) |
           (unsigned long long)(0xFFFFFFFFu - i);
}

__device__ __forceinline__ unsigned shadow_ld(const unsigned* p) {
    return __hip_atomic_load(p, __ATOMIC_RELAXED, __HIP_MEMORY_SCOPE_WORKGROUP);
}
__device__ __forceinline__ void shadow_st(unsigned* p, unsigned v) {
    __hip_atomic_store(p, v, __ATOMIC_RELAXED, __HIP_MEMORY_SCOPE_WORKGROUP);
}

// Pass 1: pred-only stream; high edges gather dst and atomicMax into tbl.
__global__ void seed_pass(const float* __restrict__ pred,
                          const int* __restrict__ dst,
                          unsigned long long* __restrict__ tbl,
                          int e, unsigned tbits) {
    const int nvec = e >> 2;
    const int T = gridDim.x * blockDim.x;
    const int t = blockIdx.x * blockDim.x + threadIdx.x;

    fx4 p[CH];
    int vi[CH];
    bool ok[CH];
    #pragma unroll
    for (int c = 0; c < CH; ++c) {
        vi[c] = t + c * T;
        ok[c] = vi[c] < nvec;
        p[c] = ((const fx4*)pred)[ok[c] ? vi[c] : 0];
    }
    #pragma unroll
    for (int c = 0; c < CH; ++c) {
        unsigned pbv[4] = {__float_as_uint(p[c].x), __float_as_uint(p[c].y),
                           __float_as_uint(p[c].z), __float_as_uint(p[c].w)};
        unsigned base = (unsigned)(vi[c] << 2);
        #pragma unroll
        for (int k = 0; k < 4; ++k) {
            if (ok[c] && pbv[k] >= tbits) {
                int d = dst[base + k];              // sparse gather (~3%)
                (void)__hip_atomic_fetch_max(&tbl[d], pack64(pbv[k], base + k),
                                             __ATOMIC_RELAXED,
                                             __HIP_MEMORY_SCOPE_AGENT);
            }
        }
    }
}

// Pass 2: bitmap from tbl — bit i set iff node i saw a >=t edge in seed.
// Thread 0 also zeroes `found` (replaces a 1-float memset dispatch).
__global__ void bitmap_pass(const unsigned long long* __restrict__ tbl,
                            unsigned long long* __restrict__ bmp,
                            float* __restrict__ found,
                            int n, unsigned tbits) {
    int node = blockIdx.x * blockDim.x + threadIdx.x;
    if (node == 0) *found = 0.0f;
    bool set = (node < n) && ((unsigned)(tbl[node] >> 32) >= tbits);
    unsigned long long mask = __ballot(set);
    if ((threadIdx.x & 63) == 0) {
        int w = node >> 6;
        if (w < ((n + 63) >> 6)) bmp[w] = mask;
    }
}

// Pass 3: low edges only; bitmap fast-skip, shd slow path for unseeded nodes.
__global__ void main_pass(const float* __restrict__ pred,
                          const int* __restrict__ dst,
                          unsigned long long* __restrict__ tbl,
                          unsigned* __restrict__ shd,
                          const unsigned long long* __restrict__ bmp,
                          int e, int n, unsigned tbits) {
    extern __shared__ unsigned long long lbmp[];
    const int nwords = (n + 63) >> 6;
    for (int w = threadIdx.x; w < nwords; w += blockDim.x)
        lbmp[w] = bmp[w];
    __syncthreads();

    const int nvec = e >> 2;
    const int T = gridDim.x * blockDim.x;
    const int t = blockIdx.x * blockDim.x + threadIdx.x;

    fx4 p[CH];
    ix4 d[CH];
    int vi[CH];
    bool ok[CH];
    #pragma unroll
    for (int c = 0; c < CH; ++c) {
        vi[c] = t + c * T;
        ok[c] = vi[c] < nvec;
        int a = ok[c] ? vi[c] : 0;
        p[c] = ((const fx4*)pred)[a];
        d[c] = ((const ix4*)dst)[a];
    }

    #pragma unroll
    for (int c = 0; c < CH; ++c) {
        unsigned pbv[4] = {__float_as_uint(p[c].x), __float_as_uint(p[c].y),
                           __float_as_uint(p[c].z), __float_as_uint(p[c].w)};
        int dv[4] = {d[c].x, d[c].y, d[c].z, d[c].w};
        unsigned base = (unsigned)(vi[c] << 2);

        bool slow[4];
        unsigned cc[4] = {0, 0, 0, 0};
        #pragma unroll
        for (int k = 0; k < 4; ++k) {
            bool low = ok[c] && (pbv[k] < tbits);       // high edges done in seed
            bool seeded = (lbmp[dv[k] >> 6] >> (dv[k] & 63)) & 1ULL;
            slow[k] = low && !seeded;
        }
        #pragma unroll
        for (int k = 0; k < 4; ++k)
            if (slow[k]) cc[k] = shadow_ld(&shd[dv[k]]);   // MLP on residual
        #pragma unroll
        for (int k = 0; k < 4; ++k) {
            if (slow[k] && pbv[k] >= cc[k]) {
                (void)__hip_atomic_fetch_max(&tbl[dv[k]],
                                             pack64(pbv[k], base + k),
                                             __ATOMIC_RELAXED,
                                             __HIP_MEMORY_SCOPE_AGENT);
                shadow_st(&shd[dv[k]], pbv[k]);  // throttle unseeded cascades
            }
        }
    }

    // Tail (e % 4 edges): one thread, exact (idempotent max).
    if (blockIdx.x == 0 && threadIdx.x == 0) {
        for (int i = (nvec << 2); i < e; ++i) {
            unsigned pb_ = __float_as_uint(pred[i]);
            int dd = dst[i];
            if (pb_ >= shadow_ld(&shd[dd])) {
                (void)__hip_atomic_fetch_max(&tbl[dd], pack64(pb_, (unsigned)i),
                                             __ATOMIC_RELAXED,
                                             __HIP_MEMORY_SCOPE_AGENT);
                shadow_st(&shd[dd], pb_);
            }
        }
    }
}

__global__ void node_kernel(const unsigned long long* __restrict__ best,
                            const int* __restrict__ matched,
                            const int* __restrict__ src,
                            float* __restrict__ out_matched,
                            float* __restrict__ out_winpred,
                            float* __restrict__ found,
                            int n) {
    int i = blockIdx.x * blockDim.x + threadIdx.x;
    if (i >= n) return;
    unsigned long long b = best[i];
    int m = matched[i];
    int nm = m;
    float wp = 0.0f;
    if (b != 0ULL) {
        wp = __uint_as_float((unsigned int)(b >> 32));
        unsigned int idx = 0xFFFFFFFFu - (unsigned int)(b & 0xFFFFFFFFu);
        if (m == -1 && wp > 0.5f) {
            nm = matched[src[idx]];
            *found = 1.0f;   // benign race: every writer stores 1.0f
        }
    }
    out_matched[i] = (float)nm;
    out_winpred[i] = wp;
}

extern "C" void kernel_launch(void* const* d_in, const int* in_sizes, int n_in,
                              void* d_out, int out_size, void* d_ws, size_t ws_size,
                              hipStream_t stream) {
    const float* edge_pred = (const float*)d_in[0];
    const int*   edge_index = (const int*)d_in[1];   // [2, E]: row0 = src, row1 = dst
    const int*   matched   = (const int*)d_in[2];

    const int e = in_sizes[0];
    const int n = in_sizes[2];

    const int* src = edge_index;
    const int* dst = edge_index + e;

    // ws layout: [ u64 tbl[n] | u32 shd[n] | u64 bmp[ceil(n/64)] ]
    unsigned long long* tbl = (unsigned long long*)d_ws;
    unsigned* shd = (unsigned*)(tbl + n);
    unsigned long long* bmp = (unsigned long long*)(shd + n);
    const int nwords = (n + 63) >> 6;

    float* out_matched = (float*)d_out;
    float* out_winpred = out_matched + n;
    float* found       = out_matched + 2 * n;

    (void)hipMemsetAsync(tbl, 0, (size_t)n * 12, stream);  // tbl + shd

    float ts = 0.97f;
    unsigned tbits;
    memcpy(&tbits, &ts, sizeof(tbits));

    const int block = 512;
    const int nvec = e >> 2;

    int grid_e = ((nvec + CH - 1) / CH + block - 1) / block;
    if (grid_e < 1) grid_e = 1;

    seed_pass<<<grid_e, block, 0, stream>>>(edge_pred, dst, tbl, e, tbits);

    int grid_b = (n + block - 1) / block;
    bitmap_pass<<<grid_b, block, 0, stream>>>(tbl, bmp, found, n, tbits);

    const size_t lds_bytes = (size_t)nwords * sizeof(unsigned long long);
    main_pass<<<grid_e, block, lds_bytes, stream>>>(
        edge_pred, dst, tbl, shd, bmp, e, n, tbits);

    int grid_n = (n + 255) / 256;
    node_kernel<<<grid_n, 256, 0, stream>>>(tbl, matched, src,
                                            out_matched, out_winpred, found, n);
}